// Round 7
// baseline (18.735 us; speedup 1.0000x reference)
//
#include <hip/hip_runtime.h>

#define WORD_LEN 16
#define BLOCK 512

// 8-way bank-quad replicated table: entry (id, h, g) at float4 index
// id*16 + h*8 + g  -> byte addr = id*256 + h*128 + g*16, so (addr/16)%8 == g.
// Lane reads copy g = tid&7: every ds_read_b128 stays inside its own bank
// quad -> exactly 8 lanes x 4 dwords per quad = 8 passes = the b128 floor,
// conflict-free for ANY id distribution. 64 KB -> 2 blocks/CU, 4 waves/SIMD.
__global__ __launch_bounds__(BLOCK, 4) void oct_word_emb_kernel(
    const int* __restrict__ ids,
    const float* __restrict__ emb,
    float* __restrict__ out)
{
    __shared__ float4 tab[256 * 16];   // 64 KB

    const int tid = threadIdx.x;

    // ---- stage embedding: thread t -> row id = t/2, half h = t%2, 8 copies.
    // g rotated by tid so each write instr covers all 8 quads (conflict-free).
    {
        const int id = tid >> 1;
        const int h  = tid & 1;
        const float4* e4 = reinterpret_cast<const float4*>(emb);
        float4 lo = e4[id * 2 + 0];    // emb[id][0..3]
        float4 hi = e4[id * 2 + 1];    // emb[id][4..7]
        const float4 val = h ? make_float4(hi.y, hi.z, hi.w, 0.0f)    // imag 5..7
                             : make_float4(lo.y, lo.z, lo.w, hi.x);   // imag 1..4
        const int base = id * 16 + h * 8;
        #pragma unroll
        for (int gg = 0; gg < 8; ++gg) {
            const int g = (gg + tid) & 7;
            tab[base + g] = val;
        }
    }
    __syncthreads();

    const int g = tid & 7;                       // this lane's bank quad
    const float4* mytab = tab + g;               // lo at mytab[id*16], hi at +8

    const size_t w = (size_t)blockIdx.x * BLOCK + tid;

    // 16 ids: 4x int4 = this thread's own 64B line (R5 proved LDS-staging these
    // is a loss; direct loads + L1 handle it).
    const int4* g4 = reinterpret_cast<const int4*>(ids) + w * 4;
    const int4 w0 = g4[0], w1 = g4[1], w2 = g4[2], w3 = g4[3];
    const int id[16] = {w0.x, w0.y, w0.z, w0.w,  w1.x, w1.y, w1.z, w1.w,
                        w2.x, w2.y, w2.z, w2.w,  w3.x, w3.y, w3.z, w3.w};

    float v0, v1, v2, v3, v4, v5, v6;
    {
        const float4 a = mytab[id[0] * 16];
        const float4 h = mytab[id[0] * 16 + 8];
        v0 = a.x; v1 = a.y; v2 = a.z; v3 = a.w;
        v4 = h.x; v5 = h.y; v6 = h.z;
    }

    #pragma unroll
    for (int t = 1; t < WORD_LEN; ++t) {
        const float4 aa = mytab[id[t] * 16];
        const float4 hh = mytab[id[t] * 16 + 8];
        const float x0 = aa.x, x1 = aa.y, x2 = aa.z, x3 = aa.w;
        const float x4 = hh.x, x5 = hh.y, x6 = hh.z;

        // Fano 7D cross, per-component (1 mul + 5 fma, no zero-init movs).
        float r0 = v1 * x2;  r0 = fmaf(-v2, x1, r0);  r0 = fmaf(v3, x4, r0);
        r0 = fmaf(-v4, x3, r0);  r0 = fmaf(v6, x5, r0);  r0 = fmaf(-v5, x6, r0);
        float r1 = v2 * x0;  r1 = fmaf(-v0, x2, r1);  r1 = fmaf(v3, x5, r1);
        r1 = fmaf(-v5, x3, r1);  r1 = fmaf(v4, x6, r1);  r1 = fmaf(-v6, x4, r1);
        float r2 = v0 * x1;  r2 = fmaf(-v1, x0, r2);  r2 = fmaf(v3, x6, r2);
        r2 = fmaf(-v6, x3, r2);  r2 = fmaf(v5, x4, r2);  r2 = fmaf(-v4, x5, r2);
        float r3 = v4 * x0;  r3 = fmaf(-v0, x4, r3);  r3 = fmaf(v5, x1, r3);
        r3 = fmaf(-v1, x5, r3);  r3 = fmaf(v6, x2, r3);  r3 = fmaf(-v2, x6, r3);
        float r4 = v0 * x3;  r4 = fmaf(-v3, x0, r4);  r4 = fmaf(v6, x1, r4);
        r4 = fmaf(-v1, x6, r4);  r4 = fmaf(v2, x5, r4);  r4 = fmaf(-v5, x2, r4);
        float r5 = v0 * x6;  r5 = fmaf(-v6, x0, r5);  r5 = fmaf(v1, x3, r5);
        r5 = fmaf(-v3, x1, r5);  r5 = fmaf(v4, x2, r5);  r5 = fmaf(-v2, x4, r5);
        float r6 = v5 * x0;  r6 = fmaf(-v0, x5, r6);  r6 = fmaf(v1, x4, r6);
        r6 = fmaf(-v4, x1, r6);  r6 = fmaf(v2, x3, r6);  r6 = fmaf(-v3, x2, r6);

        v0 = r0; v1 = r1; v2 = r2; v3 = r3; v4 = r4; v5 = r5; v6 = r6;
    }

    float* o = out + w * 7;
    o[0] = v0; o[1] = v1; o[2] = v2; o[3] = v3; o[4] = v4; o[5] = v5; o[6] = v6;
}

extern "C" void kernel_launch(void* const* d_in, const int* in_sizes, int n_in,
                              void* d_out, int out_size, void* d_ws, size_t ws_size,
                              hipStream_t stream) {
    const int* ids = (const int*)d_in[0];      // (524288, 16) int32
    const float* emb = (const float*)d_in[1];  // (256, 8) fp32
    float* out = (float*)d_out;                // (524288, 7) fp32

    const int batch = in_sizes[0] / WORD_LEN;  // 524288
    const int grid = batch / BLOCK;            // 1024

    oct_word_emb_kernel<<<grid, BLOCK, 0, stream>>>(ids, emb, out);
}